// Round 12
// baseline (140.115 us; speedup 1.0000x reference)
//
#include <hip/hip_runtime.h>
#include <hip/hip_bf16.h>
#include <stdint.h>

typedef __attribute__((ext_vector_type(8))) _Float16 half8;
typedef __attribute__((ext_vector_type(4))) _Float16 half4;
typedef __attribute__((ext_vector_type(2))) __fp16 fp16x2;
typedef __attribute__((ext_vector_type(4))) float f32x4;
typedef __attribute__((ext_vector_type(16))) float f32x16;
typedef __attribute__((ext_vector_type(4))) float float4v;

#define DEVI static __device__ __forceinline__

constexpr int Bb = 16, Nn = 2048, Cc = 256, Dd = 256;

DEVI unsigned short f2h_bits(float f) {
  _Float16 h = (_Float16)f;
  union { _Float16 h; unsigned short u; } c;
  c.h = h;
  return c.u;
}

DEVI void gl_lds16(const void* gsrc, void* ldst) {
  __builtin_amdgcn_global_load_lds(
      (const __attribute__((address_space(1))) unsigned int*)gsrc,
      (__attribute__((address_space(3))) unsigned int*)ldst, 16, 0, 0);
}

DEVI f32x4 mfma16h(half8 a, half8 b, f32x4 c) {
  return __builtin_amdgcn_mfma_f32_16x16x32_f16(a, b, c, 0, 0, 0);
}
DEVI f32x16 mfma32h(half8 a, half8 b, f32x16 c) {
  return __builtin_amdgcn_mfma_f32_32x32x16_f16(a, b, c, 0, 0, 0);
}

DEVI unsigned int pkrtz(float a, float b) {
  union { fp16x2 h; unsigned int u; } c;
  c.h = __builtin_amdgcn_cvt_pkrtz(a, b);
  return c.u;
}

// ---------- kernel 0: fused x->fp16 and W->fp16 split ----------
__global__ void k_split(const float* __restrict__ x, const float* __restrict__ wq,
                        const float* __restrict__ wk, const float* __restrict__ wv,
                        _Float16* __restrict__ xh, _Float16* __restrict__ wh) {
  int i = blockIdx.x * 256 + threadIdx.x;
  if (i < 2097152) {
    float4v v = reinterpret_cast<const float4v*>(x)[i];
    half4 h;
#pragma unroll
    for (int j = 0; j < 4; ++j) h[j] = (_Float16)v[j];
    reinterpret_cast<half4*>(xh)[i] = h;
  } else {
    int ii = i - 2097152;
    int mat = ii >> 16;
    int rem = ii & 65535;
    const float* w = (mat == 0) ? wq : ((mat == 1) ? wk : wv);
    wh[(size_t)mat * 65536 + rem] = (_Float16)w[rem];
  }
}

// ---------- kernel 1: QKV projection GEMM (fp16 in, f32 acc) ----------
__global__ __launch_bounds__(256, 2) void k_qkv(
    const _Float16* __restrict__ xh, const _Float16* __restrict__ wh,
    const float* __restrict__ bq, const float* __restrict__ bk, const float* __restrict__ bv,
    _Float16* __restrict__ qout, _Float16* __restrict__ kout, _Float16* __restrict__ vt) {
  __shared__ __align__(16) unsigned short smem[17408];

  const int tid = threadIdx.x;
  const int m0 = blockIdx.x * 128;
  const int n0 = blockIdx.y * 128;
  const int mat = blockIdx.z;
  const _Float16* wmat = wh + (size_t)mat * 65536;
  const int wave = tid >> 6, lane = tid & 63;
  const int wr = wave >> 1, wc = wave & 1;
  const int l15 = lane & 15, lq = lane >> 4;

  f32x4 zero4 = {0.f, 0.f, 0.f, 0.f};
  f32x4 acc[4][4];
#pragma unroll
  for (int a = 0; a < 4; ++a)
#pragma unroll
    for (int b2 = 0; b2 < 4; ++b2) acc[a][b2] = zero4;

  char* As = (char*)smem;
  char* Bs = (char*)smem + 16384;

  for (int kc = 0; kc < 4; ++kc) {
#pragma unroll
    for (int i = 0; i < 4; ++i) {
      int p = i * 4096 + tid * 16;
      int row = p >> 7;
      int src_in_row = (p & 127) ^ ((row & 7) << 4);
      const char* g = (const char*)(xh + (size_t)(m0 + row) * Cc + kc * 64) + src_in_row;
      gl_lds16(g, As + p);
    }
#pragma unroll
    for (int i = 0; i < 4; ++i) {
      int p = i * 4096 + tid * 16;
      int row = p >> 7;
      int src_in_row = (p & 127) ^ ((row & 7) << 4);
      const char* g = (const char*)(wmat + (size_t)(n0 + row) * Cc + kc * 64) + src_in_row;
      gl_lds16(g, Bs + p);
    }
    __syncthreads();
#pragma unroll
    for (int ks = 0; ks < 2; ++ks) {
      half8 af[4], bfr[4];
#pragma unroll
      for (int mf = 0; mf < 4; ++mf) {
        int row = wr * 64 + mf * 16 + l15;
        int byte = (row * 128 + ks * 64 + lq * 16) ^ ((row & 7) << 4);
        af[mf] = *(const half8*)(As + byte);
      }
#pragma unroll
      for (int nf = 0; nf < 4; ++nf) {
        int row = wc * 64 + nf * 16 + l15;
        int byte = (row * 128 + ks * 64 + lq * 16) ^ ((row & 7) << 4);
        bfr[nf] = *(const half8*)(Bs + byte);
      }
#pragma unroll
      for (int mf = 0; mf < 4; ++mf)
#pragma unroll
        for (int nf = 0; nf < 4; ++nf) acc[mf][nf] = mfma16h(af[mf], bfr[nf], acc[mf][nf]);
    }
    __syncthreads();
  }

  const float* bias = (mat == 0) ? bq : ((mat == 1) ? bk : bv);
  if (mat < 2) {
    _Float16* oo = (mat == 0) ? qout : kout;
#pragma unroll
    for (int nf = 0; nf < 4; ++nf) {
      int col = n0 + wc * 64 + nf * 16 + l15;
      float bval = bias[col];
#pragma unroll
      for (int mf = 0; mf < 4; ++mf) {
        int grow = m0 + wr * 64 + mf * 16 + lq * 4;
#pragma unroll
        for (int r = 0; r < 4; ++r)
          oo[(size_t)(grow + r) * Dd + col] = (_Float16)(acc[mf][nf][r] + bval);
      }
    }
  } else {
    __syncthreads();
#pragma unroll
    for (int nf = 0; nf < 4; ++nf) {
      int dl = wc * 64 + nf * 16 + l15;
      float bval = bias[n0 + dl];
#pragma unroll
      for (int mf = 0; mf < 4; ++mf) {
        int nl = wr * 64 + mf * 16 + lq * 4;
#pragma unroll
        for (int r = 0; r < 4; ++r) smem[dl * 136 + nl + r] = f2h_bits(acc[mf][nf][r] + bval);
      }
    }
    __syncthreads();
    const int bbat = m0 >> 11, tok0 = m0 & 2047;
#pragma unroll
    for (int pss = 0; pss < 8; ++pss) {
      int idx = pss * 256 + tid;
      int dl = idx >> 4;
      int cu = idx & 15;
      half8 vval = *(const half8*)((const char*)smem + dl * 272 + cu * 16);
      size_t off = ((size_t)bbat * Dd + n0 + dl) * Nn + tok0 + cu * 8;
      *(half8*)(vt + off) = vval;
    }
  }
}

// ---------- kernel 1.5: LPT ordering of 512 (b, q0, kh) items ----------
// item = b*32 + qi*2 + kh. nt depends on (b,kh) only. Rank desc by nt.
__global__ void k_order(const int* __restrict__ vlen, int* __restrict__ order) {
  __shared__ int nts[512];
  int t = threadIdx.x;
  int b = t >> 5, kh = t & 1;
  int L = vlen[b];
  int Lk = (L == 0) ? Nn : L;
  int avail = Lk - kh * 1024;
  int nt = (avail > 0) ? ((avail + 63) >> 6) : 0;
  nt = nt > 16 ? 16 : nt;
  nts[t] = nt;
  __syncthreads();
  int rank = 0;
  for (int j = 0; j < 512; ++j) {
    int nj = nts[j];
    if (nj > nt || (nj == nt && j < t)) ++rank;
  }
  order[rank] = t;
}

// ---------- kernel 2a: flash attention partial, round-7 engine ----------
// 256 blocks x 512 thr (8 waves = 4 wq x 2 wk), BQ=128, dbuf KV, counted
// vmcnt. Block i processes items order[i] and order[511-i] (LPT folded
// pairing -> each CU gets ~equal total tiles). Each item = (b, 128 q rows,
// one 1024-key half, <=16 tiles). Writes normalized fp16 O partial + (m,l).
__global__ __launch_bounds__(512, 2) void k_attn_f(
    const _Float16* __restrict__ qg, const _Float16* __restrict__ kin,
    const _Float16* __restrict__ vt, const int* __restrict__ vlen,
    const int* __restrict__ order, _Float16* __restrict__ Op,
    float* __restrict__ ml) {
  __shared__ __align__(16) char SMEM[149504];
  char* const KVb = SMEM;                                   // [2][65536]
  unsigned int* const PL = (unsigned int*)(SMEM + 131072);  // [4 wq][32 kp][32 q]
  float* const mex = (float*)(SMEM + 147456);               // [8][32]
  float* const lex = (float*)(SMEM + 148480);               // [8][32]

  const int tid = threadIdx.x;
  const int wave = tid >> 6, lane = tid & 63;
  const int l31 = lane & 31, h = lane >> 5;
  const int wq = wave >> 1, wk = wave & 1;

  for (int s = 0; s < 2; ++s) {
    const int item = order[s == 0 ? blockIdx.x : (511 - blockIdx.x)];
    const int b = item >> 5;
    const int q0 = ((item >> 1) & 15) * 128;
    const int kh = item & 1;
    const int kst = kh * 1024;
    const int L = vlen[b];
    const bool uni = (L == 0);
    const int Lk = uni ? Nn : L;
    const int avail = Lk - kst;
    int nt = (avail > 0) ? ((avail + 63) >> 6) : 0;
    nt = nt > 16 ? 16 : nt;
    const size_t prow = (size_t)(b * 2 + kh) * Nn + q0;

    if (nt == 0) {  // empty half: publish (m=-1e30, l=0)
      if (tid < 128) {
        ml[(prow + tid) * 2 + 0] = -1e30f;
        ml[(prow + tid) * 2 + 1] = 0.f;
      }
      continue;
    }

    const char* kbase = (const char*)(kin + (size_t)b * Nn * Dd);
    const char* vbase = (const char*)(vt + (size_t)b * Dd * Nn);
    const char* qbase = (const char*)(qg + ((size_t)b * Nn + q0) * Dd);

    auto STAGE = [&](int buf, int t) {
      char* dst = KVb + buf * 65536;
      const int k0 = kst + t * 64;
#pragma unroll
      for (int i = 0; i < 4; ++i) {
        int p = i * 8192 + tid * 16;
        int row = p >> 9;
        int sl = ((p & 511) >> 4) ^ (row & 31);
        gl_lds16(kbase + (size_t)(k0 + row) * 512 + (sl << 4), dst + p);
      }
#pragma unroll
      for (int i = 0; i < 4; ++i) {
        int p = i * 8192 + tid * 16;
        int r = p >> 9;
        int sl = ((p & 511) >> 4) ^ (r & 31);
        int cl = sl << 4;
        int d = r * 4 + (cl >> 7);
        int kbyte = cl & 127;
        gl_lds16(vbase + (size_t)d * (Nn * 2) + (size_t)k0 * 2 + kbyte, dst + 32768 + p);
      }
    };

    STAGE(0, 0);
#pragma unroll
    for (int i = 0; i < 8; ++i) {
      int p = i * 8192 + tid * 16;
      int row = p >> 9;
      int sl = ((p & 511) >> 4) ^ (row & 31);
      gl_lds16(qbase + (size_t)row * 512 + (sl << 4), KVb + 65536 + p);
    }
    asm volatile("s_waitcnt vmcnt(0)" ::: "memory");
    asm volatile("s_barrier" ::: "memory");

    half8 qreg[16];
    {
      const int row = wq * 32 + l31;
#pragma unroll
      for (int kt = 0; kt < 16; ++kt) {
        int byte = row * 512 + (((kt * 2 + h) ^ (row & 31)) << 4);
        qreg[kt] = *(const half8*)(KVb + 65536 + byte);
      }
    }
    asm volatile("s_waitcnt lgkmcnt(0)" ::: "memory");
    asm volatile("s_barrier" ::: "memory");

    f32x16 acc[4];
#pragma unroll
    for (int dg = 0; dg < 4; ++dg)
#pragma unroll
      for (int r = 0; r < 16; ++r) acc[dg][r] = 0.f;
    float m = -__builtin_inff();
    float lsum = 0.f;

    for (int t = 0; t < nt; ++t) {
      const int cur = t & 1;
      if (t + 1 < nt) {
        STAGE(cur ^ 1, t + 1);
        asm volatile("s_waitcnt vmcnt(8)" ::: "memory");
      } else {
        asm volatile("s_waitcnt vmcnt(0)" ::: "memory");
      }
      asm volatile("s_barrier" ::: "memory");  // A: tile t ready

      const char* Ks = KVb + cur * 65536;
      const char* Vs = Ks + 32768;
      const int k0 = kst + t * 64;

      f32x16 st;
#pragma unroll
      for (int r = 0; r < 16; ++r) st[r] = 0.f;
      if (!uni) {
        const int key = wk * 32 + l31;
        __builtin_amdgcn_s_setprio(1);
#pragma unroll
        for (int kt = 0; kt < 16; ++kt) {
          int byte = key * 512 + (((kt * 2 + h) ^ l31) << 4);
          half8 kf = *(const half8*)(Ks + byte);
          st = mfma32h(kf, qreg[kt], st);
        }
        __builtin_amdgcn_s_setprio(0);
        if (k0 + 64 > L) {
#pragma unroll
          for (int r = 0; r < 16; ++r) {
            int keyg = k0 + wk * 32 + (r & 3) + 8 * (r >> 2) + 4 * h;
            if (keyg >= L) st[r] = -1e6f;
          }
        }
      }

      float pm = st[0];
#pragma unroll
      for (int r = 1; r < 16; ++r) pm = fmaxf(pm, st[r]);
      pm = fmaxf(pm, __shfl_xor(pm, 32));
      if (lane < 32) mex[wave * 32 + lane] = pm;
      asm volatile("s_waitcnt lgkmcnt(0)\ns_barrier" ::: "memory");  // B
      float pmo = mex[(wave ^ 1) * 32 + l31];
      float mnew = fmaxf(m, fmaxf(pm, pmo));
      float scale = __expf(m - mnew);
      m = mnew;
      float psum = 0.f;
#pragma unroll
      for (int r = 0; r < 16; ++r) {
        float p_ = __expf(st[r] - mnew);
        st[r] = p_;
        psum += p_;
      }
      lsum = lsum * scale + psum;

#pragma unroll
      for (int i = 0; i < 8; ++i) {
        unsigned int pk = pkrtz(st[2 * i], st[2 * i + 1]);
        int kp = wk * 16 + 4 * (i >> 1) + (i & 1) + 2 * h;
        PL[wq * 1024 + kp * 32 + l31] = pk;
      }
      asm volatile("s_waitcnt lgkmcnt(0)\ns_barrier" ::: "memory");  // C

      union { unsigned int u[4]; half8 v; } pf0, pf1, pf2, pf3;
#pragma unroll
      for (int w = 0; w < 4; ++w) {
        pf0.u[w] = PL[wq * 1024 + (0 * 8 + h * 4 + w) * 32 + l31];
        pf1.u[w] = PL[wq * 1024 + (1 * 8 + h * 4 + w) * 32 + l31];
        pf2.u[w] = PL[wq * 1024 + (2 * 8 + h * 4 + w) * 32 + l31];
        pf3.u[w] = PL[wq * 1024 + (3 * 8 + h * 4 + w) * 32 + l31];
      }

#pragma unroll
      for (int dg = 0; dg < 4; ++dg)
#pragma unroll
        for (int r = 0; r < 16; ++r) acc[dg][r] *= scale;

      __builtin_amdgcn_s_setprio(1);
#pragma unroll
      for (int dg = 0; dg < 4; ++dg) {
        int r = wk * 32 + dg * 8 + (l31 >> 2);
#pragma unroll
        for (int ks = 0; ks < 4; ++ks) {
          int slot = (l31 & 3) * 8 + ks * 2 + h;
          half8 vf = *(const half8*)(Vs + r * 512 + ((slot ^ (r & 31)) << 4));
          acc[dg] = mfma32h(vf, ks == 0 ? pf0.v : (ks == 1 ? pf1.v : (ks == 2 ? pf2.v : pf3.v)),
                            acc[dg]);
        }
      }
      __builtin_amdgcn_s_setprio(0);

      asm volatile("s_barrier" ::: "memory");  // D
    }

    // epilogue: l combine, publish (m,l), write normalized fp16 O partial
    lsum += __shfl_xor(lsum, 32);
    if (lane < 32) lex[wave * 32 + lane] = lsum;
    asm volatile("s_waitcnt lgkmcnt(0)\ns_barrier" ::: "memory");
    float ltot = lsum + lex[(wave ^ 1) * 32 + l31];
    float linv = 1.f / ltot;

    if (h == 0 && wk == 0) {
      size_t qq = prow + wq * 32 + l31;
      ml[qq * 2 + 0] = m;
      ml[qq * 2 + 1] = ltot;
    }

    _Float16* T = (_Float16*)SMEM;  // [128 q][264 fp16]
    {
      const int ql = wq * 32 + l31;
#pragma unroll
      for (int dg = 0; dg < 4; ++dg)
#pragma unroll
        for (int r = 0; r < 16; ++r) {
          int d = wk * 128 + dg * 32 + (r & 3) + 8 * (r >> 2) + 4 * h;
          T[ql * 264 + d] = (_Float16)(acc[dg][r] * linv);
        }
    }
    asm volatile("s_waitcnt lgkmcnt(0)\ns_barrier" ::: "memory");

    {
      const int rb = tid >> 6;        // 0..7
      const int c4 = (tid & 63) * 4;  // fp16 offset
#pragma unroll
      for (int i = 0; i < 16; ++i) {
        int row = rb + i * 8;
        half4 v = *(const half4*)(T + row * 264 + c4);
        *(half4*)(Op + (prow + row) * Dd + c4) = v;
      }
    }
    asm volatile("s_waitcnt lgkmcnt(0)\ns_barrier" ::: "memory");  // before next item
  }
}

// ---------- kernel 2b: combine the two key-half partials ----------
__global__ __launch_bounds__(256) void k_comb(const _Float16* __restrict__ Op,
                                              const float* __restrict__ ml,
                                              float* __restrict__ out) {
  int rid = blockIdx.x * 4 + (threadIdx.x >> 6);  // b*2048+q
  int lane = threadIdx.x & 63;
  int b = rid >> 11, q = rid & 2047;
  size_t i0 = (size_t)(b * 2 + 0) * Nn + q;
  size_t i1 = (size_t)(b * 2 + 1) * Nn + q;
  float m0 = ml[i0 * 2], l0 = ml[i0 * 2 + 1];
  float m1 = ml[i1 * 2], l1 = ml[i1 * 2 + 1];
  float M = fmaxf(m0, m1);
  float c0 = (l0 > 0.f) ? __expf(m0 - M) * l0 : 0.f;
  float c1 = (l1 > 0.f) ? __expf(m1 - M) * l1 : 0.f;
  float inv = 1.f / (c0 + c1);
  c0 *= inv;
  c1 *= inv;
  float4v o = {0.f, 0.f, 0.f, 0.f};
  if (c0 > 0.f) {
    half4 o0 = *(const half4*)(Op + i0 * 256 + lane * 4);
#pragma unroll
    for (int j = 0; j < 4; ++j) o[j] = c0 * (float)o0[j];
  }
  if (c1 > 0.f) {
    half4 o1 = *(const half4*)(Op + i1 * 256 + lane * 4);
#pragma unroll
    for (int j = 0; j < 4; ++j) o[j] += c1 * (float)o1[j];
  }
  *(float4v*)(out + ((size_t)b * Nn + q) * 256 + lane * 4) = o;
}

// ---------- kernel 2 (fallback, ws too small): round-7-style fused ----------
__global__ __launch_bounds__(512, 2) void k_attn(
    const _Float16* __restrict__ qg, const _Float16* __restrict__ kin,
    const _Float16* __restrict__ vt, const int* __restrict__ vlen,
    float* __restrict__ out) {
  __shared__ __align__(16) char SMEM[149504];
  char* const KVb = SMEM;
  unsigned int* const PL = (unsigned int*)(SMEM + 131072);
  float* const mex = (float*)(SMEM + 147456);
  float* const lex = (float*)(SMEM + 148480);

  const int tid = threadIdx.x;
  const int wave = tid >> 6, lane = tid & 63;
  const int l31 = lane & 31, h = lane >> 5;
  const int wq = wave >> 1, wk = wave & 1;
  const int id = blockIdx.x;
  const int g = id & 7;
  const int j = id >> 3;
  const int b = g + 8 * (j >> 4);
  const int q0 = (j & 15) * 128;
  const int L = vlen[b];
  const bool uni = (L == 0);
  const int Lk = uni ? Nn : L;
  const int nt = (Lk + 63) >> 6;

  const char* kbase = (const char*)(kin + (size_t)b * Nn * Dd);
  const char* vbase = (const char*)(vt + (size_t)b * Dd * Nn);
  const char* qbase = (const char*)(qg + ((size_t)b * Nn + q0) * Dd);

  auto STAGE = [&](int buf, int t) {
    char* dst = KVb + buf * 65536;
    const int k0 = t * 64;
#pragma unroll
    for (int i = 0; i < 4; ++i) {
      int p = i * 8192 + tid * 16;
      int row = p >> 9;
      int sl = ((p & 511) >> 4) ^ (row & 31);
      gl_lds16(kbase + (size_t)(k0 + row) * 512 + (sl << 4), dst + p);
    }
#pragma unroll
    for (int i = 0; i < 4; ++i) {
      int p = i * 8192 + tid * 16;
      int r = p >> 9;
      int sl = ((p & 511) >> 4) ^ (r & 31);
      int cl = sl << 4;
      int d = r * 4 + (cl >> 7);
      int kbyte = cl & 127;
      gl_lds16(vbase + (size_t)d * (Nn * 2) + (size_t)k0 * 2 + kbyte, dst + 32768 + p);
    }
  };

  STAGE(0, 0);
#pragma unroll
  for (int i = 0; i < 8; ++i) {
    int p = i * 8192 + tid * 16;
    int row = p >> 9;
    int sl = ((p & 511) >> 4) ^ (row & 31);
    gl_lds16(qbase + (size_t)row * 512 + (sl << 4), KVb + 65536 + p);
  }
  asm volatile("s_waitcnt vmcnt(0)" ::: "memory");
  asm volatile("s_barrier" ::: "memory");

  half8 qreg[16];
  {
    const int row = wq * 32 + l31;
#pragma unroll
    for (int kt = 0; kt < 16; ++kt) {
      int byte = row * 512 + (((kt * 2 + h) ^ (row & 31)) << 4);
      qreg[kt] = *(const half8*)(KVb + 65536 + byte);
    }
  }
  asm volatile("s_waitcnt lgkmcnt(0)" ::: "memory");
  asm volatile("s_barrier" ::: "memory");

  f32x16 acc[4];
#pragma unroll
  for (int dg = 0; dg < 4; ++dg)
#pragma unroll
    for (int r = 0; r < 16; ++r) acc[dg][r] = 0.f;
  float m = -__builtin_inff();
  float lsum = 0.f;

  for (int t = 0; t < nt; ++t) {
    const int cur = t & 1;
    if (t + 1 < nt) {
      STAGE(cur ^ 1, t + 1);
      asm volatile("s_waitcnt vmcnt(8)" ::: "memory");
    } else {
      asm volatile("s_waitcnt vmcnt(0)" ::: "memory");
    }
    asm volatile("s_barrier" ::: "memory");

    const char* Ks = KVb + cur * 65536;
    const char* Vs = Ks + 32768;
    const int k0 = t * 64;

    f32x16 st;
#pragma unroll
    for (int r = 0; r < 16; ++r) st[r] = 0.f;
    if (!uni) {
      const int key = wk * 32 + l31;
      __builtin_amdgcn_s_setprio(1);
#pragma unroll
      for (int kt = 0; kt < 16; ++kt) {
        int byte = key * 512 + (((kt * 2 + h) ^ l31) << 4);
        half8 kf = *(const half8*)(Ks + byte);
        st = mfma32h(kf, qreg[kt], st);
      }
      __builtin_amdgcn_s_setprio(0);
      if (k0 + 64 > L) {
#pragma unroll
        for (int r = 0; r < 16; ++r) {
          int keyg = k0 + wk * 32 + (r & 3) + 8 * (r >> 2) + 4 * h;
          if (keyg >= L) st[r] = -1e6f;
        }
      }
    }

    float pm = st[0];
#pragma unroll
    for (int r = 1; r < 16; ++r) pm = fmaxf(pm, st[r]);
    pm = fmaxf(pm, __shfl_xor(pm, 32));
    if (lane < 32) mex[wave * 32 + lane] = pm;
    asm volatile("s_waitcnt lgkmcnt(0)\ns_barrier" ::: "memory");
    float pmo = mex[(wave ^ 1) * 32 + l31];
    float mnew = fmaxf(m, fmaxf(pm, pmo));
    float scale = __expf(m - mnew);
    m = mnew;
    float psum = 0.f;
#pragma unroll
    for (int r = 0; r < 16; ++r) {
      float p_ = __expf(st[r] - mnew);
      st[r] = p_;
      psum += p_;
    }
    lsum = lsum * scale + psum;

#pragma unroll
    for (int i = 0; i < 8; ++i) {
      unsigned int pk = pkrtz(st[2 * i], st[2 * i + 1]);
      int kp = wk * 16 + 4 * (i >> 1) + (i & 1) + 2 * h;
      PL[wq * 1024 + kp * 32 + l31] = pk;
    }
    asm volatile("s_waitcnt lgkmcnt(0)\ns_barrier" ::: "memory");

    union { unsigned int u[4]; half8 v; } pf0, pf1, pf2, pf3;
#pragma unroll
    for (int w = 0; w < 4; ++w) {
      pf0.u[w] = PL[wq * 1024 + (0 * 8 + h * 4 + w) * 32 + l31];
      pf1.u[w] = PL[wq * 1024 + (1 * 8 + h * 4 + w) * 32 + l31];
      pf2.u[w] = PL[wq * 1024 + (2 * 8 + h * 4 + w) * 32 + l31];
      pf3.u[w] = PL[wq * 1024 + (3 * 8 + h * 4 + w) * 32 + l31];
    }

#pragma unroll
    for (int dg = 0; dg < 4; ++dg)
#pragma unroll
      for (int r = 0; r < 16; ++r) acc[dg][r] *= scale;

    __builtin_amdgcn_s_setprio(1);
#pragma unroll
    for (int dg = 0; dg < 4; ++dg) {
      int r = wk * 32 + dg * 8 + (l31 >> 2);
#pragma unroll
      for (int ks = 0; ks < 4; ++ks) {
        int slot = (l31 & 3) * 8 + ks * 2 + h;
        half8 vf = *(const half8*)(Vs + r * 512 + ((slot ^ (r & 31)) << 4));
        acc[dg] = mfma32h(vf, ks == 0 ? pf0.v : (ks == 1 ? pf1.v : (ks == 2 ? pf2.v : pf3.v)),
                          acc[dg]);
      }
    }
    __builtin_amdgcn_s_setprio(0);

    asm volatile("s_barrier" ::: "memory");
  }

  lsum += __shfl_xor(lsum, 32);
  if (lane < 32) lex[wave * 32 + lane] = lsum;
  asm volatile("s_waitcnt lgkmcnt(0)\ns_barrier" ::: "memory");
  float linv = 1.f / (lsum + lex[(wave ^ 1) * 32 + l31]);

  float* T = (float*)SMEM;
  {
    const int ql = wq * 32 + l31;
#pragma unroll
    for (int dg = 0; dg < 4; ++dg)
#pragma unroll
      for (int r = 0; r < 16; ++r) {
        int d = wk * 128 + dg * 32 + (r & 3) + 8 * (r >> 2) + 4 * h;
        T[ql * 260 + d] = acc[dg][r] * linv;
      }
  }
  asm volatile("s_waitcnt lgkmcnt(0)\ns_barrier" ::: "memory");

  {
    const int rb = tid >> 6;
    const int c4 = (tid & 63) * 4;
#pragma unroll
    for (int i = 0; i < 16; ++i) {
      int row = rb + i * 8;
      float4v v = *(const float4v*)(T + row * 260 + c4);
      *(float4v*)(out + ((size_t)b * Nn + q0 + row) * Dd + c4) = v;
    }
  }
}

// ---------- launch ----------
extern "C" void kernel_launch(void* const* d_in, const int* in_sizes, int n_in,
                              void* d_out, int out_size, void* d_ws, size_t ws_size,
                              hipStream_t stream) {
  const float* x = (const float*)d_in[0];
  const int* vlen = (const int*)d_in[1];
  const float* Wq = (const float*)d_in[2];
  const float* bq = (const float*)d_in[3];
  const float* Wk = (const float*)d_in[4];
  const float* bk = (const float*)d_in[5];
  const float* Wv = (const float*)d_in[6];
  const float* bv = (const float*)d_in[7];
  float* out = (float*)d_out;
  char* ws = (char*)d_ws;

  _Float16* qh = (_Float16*)(ws);
  _Float16* kk = (_Float16*)(ws + 16777216);
  _Float16* vt = (_Float16*)(ws + 33554432);
  _Float16* wh = (_Float16*)(ws + 50331648);
  _Float16* Op = (_Float16*)(ws + 51380224);  // 32 MB
  float* ml = (float*)(ws + 84934656);        // 512 KB
  int* order = (int*)(ws + 85458944);         // 2 KB
  _Float16* xh = (_Float16*)d_out;            // scratch; overwritten at the end

  k_split<<<8960, 256, 0, stream>>>(x, Wq, Wk, Wv, xh, wh);
  k_qkv<<<dim3(256, 2, 3), 256, 0, stream>>>(xh, wh, bq, bk, bv, qh, kk, vt);
  if (ws_size >= 85460992ull) {
    k_order<<<1, 512, 0, stream>>>(vlen, order);
    k_attn_f<<<256, 512, 0, stream>>>(qh, kk, vt, vlen, order, Op, ml);
    k_comb<<<8192, 256, 0, stream>>>(Op, ml, out);
  } else {
    k_attn<<<256, 512, 0, stream>>>(qh, kk, vt, vlen, out);
  }
}

// Round 13
// 132.122 us; speedup vs baseline: 1.0605x; 1.0605x over previous
//
#include <hip/hip_runtime.h>
#include <hip/hip_bf16.h>
#include <stdint.h>

typedef __attribute__((ext_vector_type(8))) _Float16 half8;
typedef __attribute__((ext_vector_type(4))) _Float16 half4;
typedef __attribute__((ext_vector_type(2))) __fp16 fp16x2;
typedef __attribute__((ext_vector_type(4))) float f32x4;
typedef __attribute__((ext_vector_type(16))) float f32x16;
typedef __attribute__((ext_vector_type(4))) float float4v;

#define DEVI static __device__ __forceinline__

constexpr int Bb = 16, Nn = 2048, Cc = 256, Dd = 256;

DEVI unsigned short f2h_bits(float f) {
  _Float16 h = (_Float16)f;
  union { _Float16 h; unsigned short u; } c;
  c.h = h;
  return c.u;
}

DEVI void gl_lds16(const void* gsrc, void* ldst) {
  __builtin_amdgcn_global_load_lds(
      (const __attribute__((address_space(1))) unsigned int*)gsrc,
      (__attribute__((address_space(3))) unsigned int*)ldst, 16, 0, 0);
}

DEVI f32x4 mfma16h(half8 a, half8 b, f32x4 c) {
  return __builtin_amdgcn_mfma_f32_16x16x32_f16(a, b, c, 0, 0, 0);
}
DEVI f32x16 mfma32h(half8 a, half8 b, f32x16 c) {
  return __builtin_amdgcn_mfma_f32_32x32x16_f16(a, b, c, 0, 0, 0);
}

DEVI unsigned int pkrtz(float a, float b) {
  union { fp16x2 h; unsigned int u; } c;
  c.h = __builtin_amdgcn_cvt_pkrtz(a, b);
  return c.u;
}

// ---------- kernel 0: fused x->fp16, W->fp16, and XCD schedule build ----------
// Blocks 0..8959: elementwise fp16 conversion. Block 8960: builds the
// balanced schedule: batches sorted by tile count, rank-i paired with
// rank-(15-i) on one XCD (equalizes per-XCD work, keeps staging L2-local);
// within each XCD the 64 (batch, q-block, key-half) items are LPT-ranked.
__global__ void k_split(const float* __restrict__ x, const float* __restrict__ wq,
                        const float* __restrict__ wk, const float* __restrict__ wv,
                        const int* __restrict__ vlen, _Float16* __restrict__ xh,
                        _Float16* __restrict__ wh, int* __restrict__ sched) {
  __shared__ int ntb[16];
  __shared__ int bofg[16];  // [g][lb] -> batch
  if (blockIdx.x == 8960) {
    int t = threadIdx.x;
    if (t < 16) {
      int L = vlen[t];
      int Lk = (L == 0) ? Nn : L;
      ntb[t] = (Lk + 63) >> 6;  // 1..32 tiles
    }
    __syncthreads();
    if (t < 16) {
      int r = 0;
      for (int j = 0; j < 16; ++j)
        if (ntb[j] > ntb[t] || (ntb[j] == ntb[t] && j < t)) ++r;
      int g = (r < 8) ? r : 15 - r;
      int lb = (r < 8) ? 0 : 1;
      bofg[g * 2 + lb] = t;
    }
    __syncthreads();
    for (int s = 0; s < 2; ++s) {
      int ti = s * 256 + t;  // 0..511
      int g = ti >> 6, li = ti & 63;
      int lb = li >> 5, qi = (li >> 1) & 15, kh = li & 1;
      int b = bofg[g * 2 + lb];
      int full = ntb[b];
      int myv = kh ? (full > 16 ? full - 16 : 0) : (full > 16 ? 16 : full);
      int r = 0;
      for (int j = 0; j < 64; ++j) {
        int bj = bofg[g * 2 + (j >> 5)];
        int fj = ntb[bj];
        int vj = (j & 1) ? (fj > 16 ? fj - 16 : 0) : (fj > 16 ? 16 : fj);
        if (vj > myv || (vj == myv && j < li)) ++r;
      }
      sched[g * 64 + r] = b * 32 + qi * 2 + kh;
    }
    return;
  }
  int i = blockIdx.x * 256 + threadIdx.x;
  if (i < 2097152) {
    float4v v = reinterpret_cast<const float4v*>(x)[i];
    half4 h;
#pragma unroll
    for (int j = 0; j < 4; ++j) h[j] = (_Float16)v[j];
    reinterpret_cast<half4*>(xh)[i] = h;
  } else {
    int ii = i - 2097152;
    int mat = ii >> 16;
    int rem = ii & 65535;
    const float* w = (mat == 0) ? wq : ((mat == 1) ? wk : wv);
    wh[(size_t)mat * 65536 + rem] = (_Float16)w[rem];
  }
}

// ---------- kernel 1: QKV projection GEMM (fp16 in, f32 acc) ----------
__global__ __launch_bounds__(256, 2) void k_qkv(
    const _Float16* __restrict__ xh, const _Float16* __restrict__ wh,
    const float* __restrict__ bq, const float* __restrict__ bk, const float* __restrict__ bv,
    _Float16* __restrict__ qout, _Float16* __restrict__ kout, _Float16* __restrict__ vt) {
  __shared__ __align__(16) unsigned short smem[17408];

  const int tid = threadIdx.x;
  const int m0 = blockIdx.x * 128;
  const int n0 = blockIdx.y * 128;
  const int mat = blockIdx.z;
  const _Float16* wmat = wh + (size_t)mat * 65536;
  const int wave = tid >> 6, lane = tid & 63;
  const int wr = wave >> 1, wc = wave & 1;
  const int l15 = lane & 15, lq = lane >> 4;

  f32x4 zero4 = {0.f, 0.f, 0.f, 0.f};
  f32x4 acc[4][4];
#pragma unroll
  for (int a = 0; a < 4; ++a)
#pragma unroll
    for (int b2 = 0; b2 < 4; ++b2) acc[a][b2] = zero4;

  char* As = (char*)smem;
  char* Bs = (char*)smem + 16384;

  for (int kc = 0; kc < 4; ++kc) {
#pragma unroll
    for (int i = 0; i < 4; ++i) {
      int p = i * 4096 + tid * 16;
      int row = p >> 7;
      int src_in_row = (p & 127) ^ ((row & 7) << 4);
      const char* g = (const char*)(xh + (size_t)(m0 + row) * Cc + kc * 64) + src_in_row;
      gl_lds16(g, As + p);
    }
#pragma unroll
    for (int i = 0; i < 4; ++i) {
      int p = i * 4096 + tid * 16;
      int row = p >> 7;
      int src_in_row = (p & 127) ^ ((row & 7) << 4);
      const char* g = (const char*)(wmat + (size_t)(n0 + row) * Cc + kc * 64) + src_in_row;
      gl_lds16(g, Bs + p);
    }
    __syncthreads();
#pragma unroll
    for (int ks = 0; ks < 2; ++ks) {
      half8 af[4], bfr[4];
#pragma unroll
      for (int mf = 0; mf < 4; ++mf) {
        int row = wr * 64 + mf * 16 + l15;
        int byte = (row * 128 + ks * 64 + lq * 16) ^ ((row & 7) << 4);
        af[mf] = *(const half8*)(As + byte);
      }
#pragma unroll
      for (int nf = 0; nf < 4; ++nf) {
        int row = wc * 64 + nf * 16 + l15;
        int byte = (row * 128 + ks * 64 + lq * 16) ^ ((row & 7) << 4);
        bfr[nf] = *(const half8*)(Bs + byte);
      }
#pragma unroll
      for (int mf = 0; mf < 4; ++mf)
#pragma unroll
        for (int nf = 0; nf < 4; ++nf) acc[mf][nf] = mfma16h(af[mf], bfr[nf], acc[mf][nf]);
    }
    __syncthreads();
  }

  const float* bias = (mat == 0) ? bq : ((mat == 1) ? bk : bv);
  if (mat < 2) {
    _Float16* oo = (mat == 0) ? qout : kout;
#pragma unroll
    for (int nf = 0; nf < 4; ++nf) {
      int col = n0 + wc * 64 + nf * 16 + l15;
      float bval = bias[col];
#pragma unroll
      for (int mf = 0; mf < 4; ++mf) {
        int grow = m0 + wr * 64 + mf * 16 + lq * 4;
#pragma unroll
        for (int r = 0; r < 4; ++r)
          oo[(size_t)(grow + r) * Dd + col] = (_Float16)(acc[mf][nf][r] + bval);
      }
    }
  } else {
    __syncthreads();
#pragma unroll
    for (int nf = 0; nf < 4; ++nf) {
      int dl = wc * 64 + nf * 16 + l15;
      float bval = bias[n0 + dl];
#pragma unroll
      for (int mf = 0; mf < 4; ++mf) {
        int nl = wr * 64 + mf * 16 + lq * 4;
#pragma unroll
        for (int r = 0; r < 4; ++r) smem[dl * 136 + nl + r] = f2h_bits(acc[mf][nf][r] + bval);
      }
    }
    __syncthreads();
    const int bbat = m0 >> 11, tok0 = m0 & 2047;
#pragma unroll
    for (int pss = 0; pss < 8; ++pss) {
      int idx = pss * 256 + tid;
      int dl = idx >> 4;
      int cu = idx & 15;
      half8 vval = *(const half8*)((const char*)smem + dl * 272 + cu * 16);
      size_t off = ((size_t)bbat * Dd + n0 + dl) * Nn + tok0 + cu * 8;
      *(half8*)(vt + off) = vval;
    }
  }
}

// ---------- kernel 2a: flash attention partial, round-7 engine ----------
// 256 blocks x 512 thr. Block (g = id&7 -> XCD, slot = id>>3) processes
// items sched[g*64+slot] and sched[g*64+63-slot] (within-XCD LPT fold).
// XCD g's 2 batches (rank-paired) = 4MB K+V = its L2 -> L2-local staging.
__global__ __launch_bounds__(512, 2) void k_attn_f(
    const _Float16* __restrict__ qg, const _Float16* __restrict__ kin,
    const _Float16* __restrict__ vt, const int* __restrict__ vlen,
    const int* __restrict__ sched, _Float16* __restrict__ Op,
    float* __restrict__ ml) {
  __shared__ __align__(16) char SMEM[149504];
  char* const KVb = SMEM;                                   // [2][65536]
  unsigned int* const PL = (unsigned int*)(SMEM + 131072);  // [4 wq][32 kp][32 q]
  float* const mex = (float*)(SMEM + 147456);               // [8][32]
  float* const lex = (float*)(SMEM + 148480);               // [8][32]

  const int tid = threadIdx.x;
  const int wave = tid >> 6, lane = tid & 63;
  const int l31 = lane & 31, h = lane >> 5;
  const int wq = wave >> 1, wk = wave & 1;
  const int g = blockIdx.x & 7;
  const int slot = blockIdx.x >> 3;  // 0..31

  for (int s = 0; s < 2; ++s) {
    const int item = sched[g * 64 + (s == 0 ? slot : 63 - slot)];
    const int b = item >> 5;
    const int q0 = ((item >> 1) & 15) * 128;
    const int kh = item & 1;
    const int kst = kh * 1024;
    const int L = vlen[b];
    const bool uni = (L == 0);
    const int Lk = uni ? Nn : L;
    const int avail = Lk - kst;
    int nt = (avail > 0) ? ((avail + 63) >> 6) : 0;
    nt = nt > 16 ? 16 : nt;
    const size_t prow = (size_t)(b * 2 + kh) * Nn + q0;

    if (nt == 0) {  // empty half: publish (m=-1e30, l=0)
      if (tid < 128) {
        ml[(prow + tid) * 2 + 0] = -1e30f;
        ml[(prow + tid) * 2 + 1] = 0.f;
      }
      continue;
    }

    const char* kbase = (const char*)(kin + (size_t)b * Nn * Dd);
    const char* vbase = (const char*)(vt + (size_t)b * Dd * Nn);
    const char* qbase = (const char*)(qg + ((size_t)b * Nn + q0) * Dd);

    auto STAGE = [&](int buf, int t) {
      char* dst = KVb + buf * 65536;
      const int k0 = kst + t * 64;
#pragma unroll
      for (int i = 0; i < 4; ++i) {
        int p = i * 8192 + tid * 16;
        int row = p >> 9;
        int sl = ((p & 511) >> 4) ^ (row & 31);
        gl_lds16(kbase + (size_t)(k0 + row) * 512 + (sl << 4), dst + p);
      }
#pragma unroll
      for (int i = 0; i < 4; ++i) {
        int p = i * 8192 + tid * 16;
        int r = p >> 9;
        int sl = ((p & 511) >> 4) ^ (r & 31);
        int cl = sl << 4;
        int d = r * 4 + (cl >> 7);
        int kbyte = cl & 127;
        gl_lds16(vbase + (size_t)d * (Nn * 2) + (size_t)k0 * 2 + kbyte, dst + 32768 + p);
      }
    };

    STAGE(0, 0);
#pragma unroll
    for (int i = 0; i < 8; ++i) {
      int p = i * 8192 + tid * 16;
      int row = p >> 9;
      int sl = ((p & 511) >> 4) ^ (row & 31);
      gl_lds16(qbase + (size_t)row * 512 + (sl << 4), KVb + 65536 + p);
    }
    asm volatile("s_waitcnt vmcnt(0)" ::: "memory");
    asm volatile("s_barrier" ::: "memory");

    half8 qreg[16];
    {
      const int row = wq * 32 + l31;
#pragma unroll
      for (int kt = 0; kt < 16; ++kt) {
        int byte = row * 512 + (((kt * 2 + h) ^ (row & 31)) << 4);
        qreg[kt] = *(const half8*)(KVb + 65536 + byte);
      }
    }
    asm volatile("s_waitcnt lgkmcnt(0)" ::: "memory");
    asm volatile("s_barrier" ::: "memory");

    f32x16 acc[4];
#pragma unroll
    for (int dg = 0; dg < 4; ++dg)
#pragma unroll
      for (int r = 0; r < 16; ++r) acc[dg][r] = 0.f;
    float m = -__builtin_inff();
    float lsum = 0.f;

    for (int t = 0; t < nt; ++t) {
      const int cur = t & 1;
      if (t + 1 < nt) {
        STAGE(cur ^ 1, t + 1);
        asm volatile("s_waitcnt vmcnt(8)" ::: "memory");
      } else {
        asm volatile("s_waitcnt vmcnt(0)" ::: "memory");
      }
      asm volatile("s_barrier" ::: "memory");  // A: tile t ready

      const char* Ks = KVb + cur * 65536;
      const char* Vs = Ks + 32768;
      const int k0 = kst + t * 64;

      f32x16 st;
#pragma unroll
      for (int r = 0; r < 16; ++r) st[r] = 0.f;
      if (!uni) {
        const int key = wk * 32 + l31;
        __builtin_amdgcn_s_setprio(1);
#pragma unroll
        for (int kt = 0; kt < 16; ++kt) {
          int byte = key * 512 + (((kt * 2 + h) ^ l31) << 4);
          half8 kf = *(const half8*)(Ks + byte);
          st = mfma32h(kf, qreg[kt], st);
        }
        __builtin_amdgcn_s_setprio(0);
        if (k0 + 64 > L) {
#pragma unroll
          for (int r = 0; r < 16; ++r) {
            int keyg = k0 + wk * 32 + (r & 3) + 8 * (r >> 2) + 4 * h;
            if (keyg >= L) st[r] = -1e6f;
          }
        }
      }

      float pm = st[0];
#pragma unroll
      for (int r = 1; r < 16; ++r) pm = fmaxf(pm, st[r]);
      pm = fmaxf(pm, __shfl_xor(pm, 32));
      if (lane < 32) mex[wave * 32 + lane] = pm;
      asm volatile("s_waitcnt lgkmcnt(0)\ns_barrier" ::: "memory");  // B
      float pmo = mex[(wave ^ 1) * 32 + l31];
      float mnew = fmaxf(m, fmaxf(pm, pmo));
      float scale = __expf(m - mnew);
      m = mnew;
      float psum = 0.f;
#pragma unroll
      for (int r = 0; r < 16; ++r) {
        float p_ = __expf(st[r] - mnew);
        st[r] = p_;
        psum += p_;
      }
      lsum = lsum * scale + psum;

#pragma unroll
      for (int i = 0; i < 8; ++i) {
        unsigned int pk = pkrtz(st[2 * i], st[2 * i + 1]);
        int kp = wk * 16 + 4 * (i >> 1) + (i & 1) + 2 * h;
        PL[wq * 1024 + kp * 32 + l31] = pk;
      }
      asm volatile("s_waitcnt lgkmcnt(0)\ns_barrier" ::: "memory");  // C

      union { unsigned int u[4]; half8 v; } pf0, pf1, pf2, pf3;
#pragma unroll
      for (int w = 0; w < 4; ++w) {
        pf0.u[w] = PL[wq * 1024 + (0 * 8 + h * 4 + w) * 32 + l31];
        pf1.u[w] = PL[wq * 1024 + (1 * 8 + h * 4 + w) * 32 + l31];
        pf2.u[w] = PL[wq * 1024 + (2 * 8 + h * 4 + w) * 32 + l31];
        pf3.u[w] = PL[wq * 1024 + (3 * 8 + h * 4 + w) * 32 + l31];
      }

#pragma unroll
      for (int dg = 0; dg < 4; ++dg)
#pragma unroll
        for (int r = 0; r < 16; ++r) acc[dg][r] *= scale;

      __builtin_amdgcn_s_setprio(1);
#pragma unroll
      for (int dg = 0; dg < 4; ++dg) {
        int r = wk * 32 + dg * 8 + (l31 >> 2);
#pragma unroll
        for (int ks = 0; ks < 4; ++ks) {
          int slotv = (l31 & 3) * 8 + ks * 2 + h;
          half8 vf = *(const half8*)(Vs + r * 512 + ((slotv ^ (r & 31)) << 4));
          acc[dg] = mfma32h(vf, ks == 0 ? pf0.v : (ks == 1 ? pf1.v : (ks == 2 ? pf2.v : pf3.v)),
                            acc[dg]);
        }
      }
      __builtin_amdgcn_s_setprio(0);

      asm volatile("s_barrier" ::: "memory");  // D
    }

    // epilogue: l combine, publish (m,l), write normalized fp16 O partial
    lsum += __shfl_xor(lsum, 32);
    if (lane < 32) lex[wave * 32 + lane] = lsum;
    asm volatile("s_waitcnt lgkmcnt(0)\ns_barrier" ::: "memory");
    float ltot = lsum + lex[(wave ^ 1) * 32 + l31];
    float linv = 1.f / ltot;

    if (h == 0 && wk == 0) {
      size_t qq = prow + wq * 32 + l31;
      ml[qq * 2 + 0] = m;
      ml[qq * 2 + 1] = ltot;
    }

    _Float16* T = (_Float16*)SMEM;  // [128 q][264 fp16]
    {
      const int ql = wq * 32 + l31;
#pragma unroll
      for (int dg = 0; dg < 4; ++dg)
#pragma unroll
        for (int r = 0; r < 16; ++r) {
          int d = wk * 128 + dg * 32 + (r & 3) + 8 * (r >> 2) + 4 * h;
          T[ql * 264 + d] = (_Float16)(acc[dg][r] * linv);
        }
    }
    asm volatile("s_waitcnt lgkmcnt(0)\ns_barrier" ::: "memory");

    {
      const int rb = tid >> 6;        // 0..7
      const int c4 = (tid & 63) * 4;  // fp16 offset
#pragma unroll
      for (int i = 0; i < 16; ++i) {
        int row = rb + i * 8;
        half4 v = *(const half4*)(T + row * 264 + c4);
        *(half4*)(Op + (prow + row) * Dd + c4) = v;
      }
    }
    asm volatile("s_waitcnt lgkmcnt(0)\ns_barrier" ::: "memory");  // before next item
  }
}

// ---------- kernel 2b: combine the two key-half partials ----------
__global__ __launch_bounds__(256) void k_comb(const _Float16* __restrict__ Op,
                                              const float* __restrict__ ml,
                                              float* __restrict__ out) {
  int rid = blockIdx.x * 4 + (threadIdx.x >> 6);  // b*2048+q
  int lane = threadIdx.x & 63;
  int b = rid >> 11, q = rid & 2047;
  size_t i0 = (size_t)(b * 2 + 0) * Nn + q;
  size_t i1 = (size_t)(b * 2 + 1) * Nn + q;
  float m0 = ml[i0 * 2], l0 = ml[i0 * 2 + 1];
  float m1 = ml[i1 * 2], l1 = ml[i1 * 2 + 1];
  float M = fmaxf(m0, m1);
  float c0 = (l0 > 0.f) ? __expf(m0 - M) * l0 : 0.f;
  float c1 = (l1 > 0.f) ? __expf(m1 - M) * l1 : 0.f;
  float inv = 1.f / (c0 + c1);
  c0 *= inv;
  c1 *= inv;
  float4v o = {0.f, 0.f, 0.f, 0.f};
  if (c0 > 0.f) {
    half4 o0 = *(const half4*)(Op + i0 * 256 + lane * 4);
#pragma unroll
    for (int j = 0; j < 4; ++j) o[j] = c0 * (float)o0[j];
  }
  if (c1 > 0.f) {
    half4 o1 = *(const half4*)(Op + i1 * 256 + lane * 4);
#pragma unroll
    for (int j = 0; j < 4; ++j) o[j] += c1 * (float)o1[j];
  }
  *(float4v*)(out + ((size_t)b * Nn + q) * 256 + lane * 4) = o;
}

// ---------- kernel 2 (fallback, ws too small): round-7-style fused ----------
__global__ __launch_bounds__(512, 2) void k_attn(
    const _Float16* __restrict__ qg, const _Float16* __restrict__ kin,
    const _Float16* __restrict__ vt, const int* __restrict__ vlen,
    float* __restrict__ out) {
  __shared__ __align__(16) char SMEM[149504];
  char* const KVb = SMEM;
  unsigned int* const PL = (unsigned int*)(SMEM + 131072);
  float* const mex = (float*)(SMEM + 147456);
  float* const lex = (float*)(SMEM + 148480);

  const int tid = threadIdx.x;
  const int wave = tid >> 6, lane = tid & 63;
  const int l31 = lane & 31, h = lane >> 5;
  const int wq = wave >> 1, wk = wave & 1;
  const int id = blockIdx.x;
  const int g = id & 7;
  const int j = id >> 3;
  const int b = g + 8 * (j >> 4);
  const int q0 = (j & 15) * 128;
  const int L = vlen[b];
  const bool uni = (L == 0);
  const int Lk = uni ? Nn : L;
  const int nt = (Lk + 63) >> 6;

  const char* kbase = (const char*)(kin + (size_t)b * Nn * Dd);
  const char* vbase = (const char*)(vt + (size_t)b * Dd * Nn);
  const char* qbase = (const char*)(qg + ((size_t)b * Nn + q0) * Dd);

  auto STAGE = [&](int buf, int t) {
    char* dst = KVb + buf * 65536;
    const int k0 = t * 64;
#pragma unroll
    for (int i = 0; i < 4; ++i) {
      int p = i * 8192 + tid * 16;
      int row = p >> 9;
      int sl = ((p & 511) >> 4) ^ (row & 31);
      gl_lds16(kbase + (size_t)(k0 + row) * 512 + (sl << 4), dst + p);
    }
#pragma unroll
    for (int i = 0; i < 4; ++i) {
      int p = i * 8192 + tid * 16;
      int r = p >> 9;
      int sl = ((p & 511) >> 4) ^ (r & 31);
      int cl = sl << 4;
      int d = r * 4 + (cl >> 7);
      int kbyte = cl & 127;
      gl_lds16(vbase + (size_t)d * (Nn * 2) + (size_t)k0 * 2 + kbyte, dst + 32768 + p);
    }
  };

  STAGE(0, 0);
#pragma unroll
  for (int i = 0; i < 8; ++i) {
    int p = i * 8192 + tid * 16;
    int row = p >> 9;
    int sl = ((p & 511) >> 4) ^ (row & 31);
    gl_lds16(qbase + (size_t)row * 512 + (sl << 4), KVb + 65536 + p);
  }
  asm volatile("s_waitcnt vmcnt(0)" ::: "memory");
  asm volatile("s_barrier" ::: "memory");

  half8 qreg[16];
  {
    const int row = wq * 32 + l31;
#pragma unroll
    for (int kt = 0; kt < 16; ++kt) {
      int byte = row * 512 + (((kt * 2 + h) ^ (row & 31)) << 4);
      qreg[kt] = *(const half8*)(KVb + 65536 + byte);
    }
  }
  asm volatile("s_waitcnt lgkmcnt(0)" ::: "memory");
  asm volatile("s_barrier" ::: "memory");

  f32x16 acc[4];
#pragma unroll
  for (int dg = 0; dg < 4; ++dg)
#pragma unroll
    for (int r = 0; r < 16; ++r) acc[dg][r] = 0.f;
  float m = -__builtin_inff();
  float lsum = 0.f;

  for (int t = 0; t < nt; ++t) {
    const int cur = t & 1;
    if (t + 1 < nt) {
      STAGE(cur ^ 1, t + 1);
      asm volatile("s_waitcnt vmcnt(8)" ::: "memory");
    } else {
      asm volatile("s_waitcnt vmcnt(0)" ::: "memory");
    }
    asm volatile("s_barrier" ::: "memory");

    const char* Ks = KVb + cur * 65536;
    const char* Vs = Ks + 32768;
    const int k0 = t * 64;

    f32x16 st;
#pragma unroll
    for (int r = 0; r < 16; ++r) st[r] = 0.f;
    if (!uni) {
      const int key = wk * 32 + l31;
      __builtin_amdgcn_s_setprio(1);
#pragma unroll
      for (int kt = 0; kt < 16; ++kt) {
        int byte = key * 512 + (((kt * 2 + h) ^ l31) << 4);
        half8 kf = *(const half8*)(Ks + byte);
        st = mfma32h(kf, qreg[kt], st);
      }
      __builtin_amdgcn_s_setprio(0);
      if (k0 + 64 > L) {
#pragma unroll
        for (int r = 0; r < 16; ++r) {
          int keyg = k0 + wk * 32 + (r & 3) + 8 * (r >> 2) + 4 * h;
          if (keyg >= L) st[r] = -1e6f;
        }
      }
    }

    float pm = st[0];
#pragma unroll
    for (int r = 1; r < 16; ++r) pm = fmaxf(pm, st[r]);
    pm = fmaxf(pm, __shfl_xor(pm, 32));
    if (lane < 32) mex[wave * 32 + lane] = pm;
    asm volatile("s_waitcnt lgkmcnt(0)\ns_barrier" ::: "memory");
    float pmo = mex[(wave ^ 1) * 32 + l31];
    float mnew = fmaxf(m, fmaxf(pm, pmo));
    float scale = __expf(m - mnew);
    m = mnew;
    float psum = 0.f;
#pragma unroll
    for (int r = 0; r < 16; ++r) {
      float p_ = __expf(st[r] - mnew);
      st[r] = p_;
      psum += p_;
    }
    lsum = lsum * scale + psum;

#pragma unroll
    for (int i = 0; i < 8; ++i) {
      unsigned int pk = pkrtz(st[2 * i], st[2 * i + 1]);
      int kp = wk * 16 + 4 * (i >> 1) + (i & 1) + 2 * h;
      PL[wq * 1024 + kp * 32 + l31] = pk;
    }
    asm volatile("s_waitcnt lgkmcnt(0)\ns_barrier" ::: "memory");

    union { unsigned int u[4]; half8 v; } pf0, pf1, pf2, pf3;
#pragma unroll
    for (int w = 0; w < 4; ++w) {
      pf0.u[w] = PL[wq * 1024 + (0 * 8 + h * 4 + w) * 32 + l31];
      pf1.u[w] = PL[wq * 1024 + (1 * 8 + h * 4 + w) * 32 + l31];
      pf2.u[w] = PL[wq * 1024 + (2 * 8 + h * 4 + w) * 32 + l31];
      pf3.u[w] = PL[wq * 1024 + (3 * 8 + h * 4 + w) * 32 + l31];
    }

#pragma unroll
    for (int dg = 0; dg < 4; ++dg)
#pragma unroll
      for (int r = 0; r < 16; ++r) acc[dg][r] *= scale;

    __builtin_amdgcn_s_setprio(1);
#pragma unroll
    for (int dg = 0; dg < 4; ++dg) {
      int r = wk * 32 + dg * 8 + (l31 >> 2);
#pragma unroll
      for (int ks = 0; ks < 4; ++ks) {
        int slotv = (l31 & 3) * 8 + ks * 2 + h;
        half8 vf = *(const half8*)(Vs + r * 512 + ((slotv ^ (r & 31)) << 4));
        acc[dg] = mfma32h(vf, ks == 0 ? pf0.v : (ks == 1 ? pf1.v : (ks == 2 ? pf2.v : pf3.v)),
                          acc[dg]);
      }
    }
    __builtin_amdgcn_s_setprio(0);

    asm volatile("s_barrier" ::: "memory");
  }

  lsum += __shfl_xor(lsum, 32);
  if (lane < 32) lex[wave * 32 + lane] = lsum;
  asm volatile("s_waitcnt lgkmcnt(0)\ns_barrier" ::: "memory");
  float linv = 1.f / (lsum + lex[(wave ^ 1) * 32 + l31]);

  float* T = (float*)SMEM;
  {
    const int ql = wq * 32 + l31;
#pragma unroll
    for (int dg = 0; dg < 4; ++dg)
#pragma unroll
      for (int r = 0; r < 16; ++r) {
        int d = wk * 128 + dg * 32 + (r & 3) + 8 * (r >> 2) + 4 * h;
        T[ql * 260 + d] = acc[dg][r] * linv;
      }
  }
  asm volatile("s_waitcnt lgkmcnt(0)\ns_barrier" ::: "memory");

  {
    const int rb = tid >> 6;
    const int c4 = (tid & 63) * 4;
#pragma unroll
    for (int i = 0; i < 16; ++i) {
      int row = rb + i * 8;
      float4v v = *(const float4v*)(T + row * 260 + c4);
      *(float4v*)(out + ((size_t)b * Nn + q0 + row) * Dd + c4) = v;
    }
  }
}

// ---------- launch ----------
extern "C" void kernel_launch(void* const* d_in, const int* in_sizes, int n_in,
                              void* d_out, int out_size, void* d_ws, size_t ws_size,
                              hipStream_t stream) {
  const float* x = (const float*)d_in[0];
  const int* vlen = (const int*)d_in[1];
  const float* Wq = (const float*)d_in[2];
  const float* bq = (const float*)d_in[3];
  const float* Wk = (const float*)d_in[4];
  const float* bk = (const float*)d_in[5];
  const float* Wv = (const float*)d_in[6];
  const float* bv = (const float*)d_in[7];
  float* out = (float*)d_out;
  char* ws = (char*)d_ws;

  _Float16* qh = (_Float16*)(ws);
  _Float16* kk = (_Float16*)(ws + 16777216);
  _Float16* vt = (_Float16*)(ws + 33554432);
  _Float16* wh = (_Float16*)(ws + 50331648);
  _Float16* Op = (_Float16*)(ws + 51380224);  // 32 MB
  float* ml = (float*)(ws + 84934656);        // 512 KB
  int* sched = (int*)(ws + 85458944);         // 2 KB
  _Float16* xh = (_Float16*)d_out;            // scratch; overwritten at the end

  k_split<<<8961, 256, 0, stream>>>(x, Wq, Wk, Wv, vlen, xh, wh, sched);
  k_qkv<<<dim3(256, 2, 3), 256, 0, stream>>>(xh, wh, bq, bk, bv, qh, kk, vt);
  if (ws_size >= 85460992ull) {
    k_attn_f<<<256, 512, 0, stream>>>(qh, kk, vt, vlen, sched, Op, ml);
    k_comb<<<8192, 256, 0, stream>>>(Op, ml, out);
  } else {
    k_attn<<<256, 512, 0, stream>>>(qh, kk, vt, vlen, out);
  }
}

// Round 14
// 126.481 us; speedup vs baseline: 1.1078x; 1.0446x over previous
//
#include <hip/hip_runtime.h>
#include <hip/hip_bf16.h>
#include <stdint.h>

typedef __attribute__((ext_vector_type(8))) _Float16 half8;
typedef __attribute__((ext_vector_type(4))) _Float16 half4;
typedef __attribute__((ext_vector_type(2))) __fp16 fp16x2;
typedef __attribute__((ext_vector_type(4))) float f32x4;
typedef __attribute__((ext_vector_type(16))) float f32x16;
typedef __attribute__((ext_vector_type(4))) float float4v;

#define DEVI static __device__ __forceinline__

constexpr int Bb = 16, Nn = 2048, Cc = 256, Dd = 256;

DEVI unsigned short f2h_bits(float f) {
  _Float16 h = (_Float16)f;
  union { _Float16 h; unsigned short u; } c;
  c.h = h;
  return c.u;
}

DEVI void gl_lds16(const void* gsrc, void* ldst) {
  __builtin_amdgcn_global_load_lds(
      (const __attribute__((address_space(1))) unsigned int*)gsrc,
      (__attribute__((address_space(3))) unsigned int*)ldst, 16, 0, 0);
}

DEVI f32x4 mfma16h(half8 a, half8 b, f32x4 c) {
  return __builtin_amdgcn_mfma_f32_16x16x32_f16(a, b, c, 0, 0, 0);
}
DEVI f32x16 mfma32h(half8 a, half8 b, f32x16 c) {
  return __builtin_amdgcn_mfma_f32_32x32x16_f16(a, b, c, 0, 0, 0);
}

DEVI unsigned int pkrtz(float a, float b) {
  union { fp16x2 h; unsigned int u; } c;
  c.h = __builtin_amdgcn_cvt_pkrtz(a, b);
  return c.u;
}

// ---------- kernel 0: fused x/W->fp16 + XCD schedule build ----------
// Block 8960 builds the schedule: batches rank-paired onto XCDs (rank-i with
// rank-15-i -> equal per-XCD work, L2-local staging). Batches with <=16 tiles
// become WHOLE items (direct f32 output, no combine); >16 split into 2 key
// halves (fp16 partial + combine). Items LPT-ranked within each XCD.
// Item encoding: (b<<6)|(qi<<2)|(kh<<1)|whole ; empty slot = -1.
__global__ void k_split(const float* __restrict__ x, const float* __restrict__ wq,
                        const float* __restrict__ wk, const float* __restrict__ wv,
                        const int* __restrict__ vlen, _Float16* __restrict__ xh,
                        _Float16* __restrict__ wh, int* __restrict__ sched) {
  __shared__ int ntb[16];
  __shared__ int bofg[16];  // [g][lb] -> batch
  if (blockIdx.x == 8960) {
    int t = threadIdx.x;
    if (t < 16) {
      int L = vlen[t];
      int Lk = (L == 0) ? Nn : L;
      ntb[t] = (Lk + 63) >> 6;  // 1..32 tiles
    }
    __syncthreads();
    if (t < 16) {
      int r = 0;
      for (int j = 0; j < 16; ++j)
        if (ntb[j] > ntb[t] || (ntb[j] == ntb[t] && j < t)) ++r;
      int g = (r < 8) ? r : 15 - r;
      int lb = (r < 8) ? 0 : 1;
      bofg[g * 2 + lb] = t;
    }
    __syncthreads();
    for (int s = 0; s < 2; ++s) {
      int ti = s * 256 + t;  // 0..511
      int g = ti >> 6, li = ti & 63;
      int lb = li >> 5, qi = (li >> 1) & 15, kh = li & 1;
      int b = bofg[g * 2 + lb];
      int full = ntb[b];
      bool sp = full > 16;
      bool valid = sp || (kh == 0);
      int sz = !valid ? -1 : (sp ? (kh ? full - 16 : 16) : full);
      int r = 0;
      for (int j = 0; j < 64; ++j) {
        int bj = bofg[g * 2 + (j >> 5)];
        int fj = ntb[bj];
        bool spj = fj > 16;
        bool vj = spj || ((j & 1) == 0);
        int zj = !vj ? -1 : (spj ? ((j & 1) ? fj - 16 : 16) : fj);
        if (zj > sz || (zj == sz && j < li)) ++r;
      }
      sched[g * 64 + r] = valid ? ((b << 6) | (qi << 2) | (kh << 1) | (sp ? 0 : 1)) : -1;
    }
    return;
  }
  int i = blockIdx.x * 256 + threadIdx.x;
  if (i < 2097152) {
    float4v v = reinterpret_cast<const float4v*>(x)[i];
    half4 h;
#pragma unroll
    for (int j = 0; j < 4; ++j) h[j] = (_Float16)v[j];
    reinterpret_cast<half4*>(xh)[i] = h;
  } else {
    int ii = i - 2097152;
    int mat = ii >> 16;
    int rem = ii & 65535;
    const float* w = (mat == 0) ? wq : ((mat == 1) ? wk : wv);
    wh[(size_t)mat * 65536 + rem] = (_Float16)w[rem];
  }
}

// ---------- kernel 1: QKV projection GEMM (fp16 in, f32 acc) ----------
__global__ __launch_bounds__(256, 2) void k_qkv(
    const _Float16* __restrict__ xh, const _Float16* __restrict__ wh,
    const float* __restrict__ bq, const float* __restrict__ bk, const float* __restrict__ bv,
    _Float16* __restrict__ qout, _Float16* __restrict__ kout, _Float16* __restrict__ vt) {
  __shared__ __align__(16) unsigned short smem[17408];

  const int tid = threadIdx.x;
  const int m0 = blockIdx.x * 128;
  const int n0 = blockIdx.y * 128;
  const int mat = blockIdx.z;
  const _Float16* wmat = wh + (size_t)mat * 65536;
  const int wave = tid >> 6, lane = tid & 63;
  const int wr = wave >> 1, wc = wave & 1;
  const int l15 = lane & 15, lq = lane >> 4;

  f32x4 zero4 = {0.f, 0.f, 0.f, 0.f};
  f32x4 acc[4][4];
#pragma unroll
  for (int a = 0; a < 4; ++a)
#pragma unroll
    for (int b2 = 0; b2 < 4; ++b2) acc[a][b2] = zero4;

  char* As = (char*)smem;
  char* Bs = (char*)smem + 16384;

  for (int kc = 0; kc < 4; ++kc) {
#pragma unroll
    for (int i = 0; i < 4; ++i) {
      int p = i * 4096 + tid * 16;
      int row = p >> 7;
      int src_in_row = (p & 127) ^ ((row & 7) << 4);
      const char* g = (const char*)(xh + (size_t)(m0 + row) * Cc + kc * 64) + src_in_row;
      gl_lds16(g, As + p);
    }
#pragma unroll
    for (int i = 0; i < 4; ++i) {
      int p = i * 4096 + tid * 16;
      int row = p >> 7;
      int src_in_row = (p & 127) ^ ((row & 7) << 4);
      const char* g = (const char*)(wmat + (size_t)(n0 + row) * Cc + kc * 64) + src_in_row;
      gl_lds16(g, Bs + p);
    }
    __syncthreads();
#pragma unroll
    for (int ks = 0; ks < 2; ++ks) {
      half8 af[4], bfr[4];
#pragma unroll
      for (int mf = 0; mf < 4; ++mf) {
        int row = wr * 64 + mf * 16 + l15;
        int byte = (row * 128 + ks * 64 + lq * 16) ^ ((row & 7) << 4);
        af[mf] = *(const half8*)(As + byte);
      }
#pragma unroll
      for (int nf = 0; nf < 4; ++nf) {
        int row = wc * 64 + nf * 16 + l15;
        int byte = (row * 128 + ks * 64 + lq * 16) ^ ((row & 7) << 4);
        bfr[nf] = *(const half8*)(Bs + byte);
      }
#pragma unroll
      for (int mf = 0; mf < 4; ++mf)
#pragma unroll
        for (int nf = 0; nf < 4; ++nf) acc[mf][nf] = mfma16h(af[mf], bfr[nf], acc[mf][nf]);
    }
    __syncthreads();
  }

  const float* bias = (mat == 0) ? bq : ((mat == 1) ? bk : bv);
  if (mat < 2) {
    _Float16* oo = (mat == 0) ? qout : kout;
#pragma unroll
    for (int nf = 0; nf < 4; ++nf) {
      int col = n0 + wc * 64 + nf * 16 + l15;
      float bval = bias[col];
#pragma unroll
      for (int mf = 0; mf < 4; ++mf) {
        int grow = m0 + wr * 64 + mf * 16 + lq * 4;
#pragma unroll
        for (int r = 0; r < 4; ++r)
          oo[(size_t)(grow + r) * Dd + col] = (_Float16)(acc[mf][nf][r] + bval);
      }
    }
  } else {
    __syncthreads();
#pragma unroll
    for (int nf = 0; nf < 4; ++nf) {
      int dl = wc * 64 + nf * 16 + l15;
      float bval = bias[n0 + dl];
#pragma unroll
      for (int mf = 0; mf < 4; ++mf) {
        int nl = wr * 64 + mf * 16 + lq * 4;
#pragma unroll
        for (int r = 0; r < 4; ++r) smem[dl * 136 + nl + r] = f2h_bits(acc[mf][nf][r] + bval);
      }
    }
    __syncthreads();
    const int bbat = m0 >> 11, tok0 = m0 & 2047;
#pragma unroll
    for (int pss = 0; pss < 8; ++pss) {
      int idx = pss * 256 + tid;
      int dl = idx >> 4;
      int cu = idx & 15;
      half8 vval = *(const half8*)((const char*)smem + dl * 272 + cu * 16);
      size_t off = ((size_t)bbat * Dd + n0 + dl) * Nn + tok0 + cu * 8;
      *(half8*)(vt + off) = vval;
    }
  }
}

// ---------- kernel 2a: flash attention, merged-exchange engine ----------
// 256 blocks x 512 thr (8 waves = 4 wq x 2 wk). 3 barriers/tile: A(tile
// ready), C(single P+pm+psum exchange), D(buf protect). l fully lane-local.
// WHOLE items write f32 out directly; split items write fp16 partial + (m,l).
__global__ __launch_bounds__(512, 2) void k_attn_f(
    const _Float16* __restrict__ qg, const _Float16* __restrict__ kin,
    const _Float16* __restrict__ vt, const int* __restrict__ vlen,
    const int* __restrict__ sched, _Float16* __restrict__ Op,
    float* __restrict__ ml, float* __restrict__ out) {
  __shared__ __align__(16) char SMEM[149504];
  char* const KVb = SMEM;                                   // [2][65536]
  unsigned int* const PL = (unsigned int*)(SMEM + 131072);  // [4 wq][32 kp][32 q]
  float* const MLX = (float*)(SMEM + 147456);               // [4 wq][2 wk][2][32]

  const int tid = threadIdx.x;
  const int wave = tid >> 6, lane = tid & 63;
  const int l31 = lane & 31, h = lane >> 5;
  const int wq = wave >> 1, wk = wave & 1;
  const int g = blockIdx.x & 7;
  const int slot = blockIdx.x >> 3;  // 0..31

  for (int s = 0; s < 2; ++s) {
    const int iw = sched[g * 64 + (s == 0 ? slot : 63 - slot)];
    if (iw < 0) continue;
    const int b = iw >> 6;
    const int q0 = ((iw >> 2) & 15) * 128;
    const int kh = (iw >> 1) & 1;
    const int whole = iw & 1;
    const int L = vlen[b];
    const bool uni = (L == 0);
    const int Lk = uni ? Nn : L;
    const int full = (Lk + 63) >> 6;
    const int kst = whole ? 0 : kh * 1024;
    const int nt = whole ? full : (kh ? full - 16 : 16);
    const size_t prow = (size_t)(b * 2 + kh) * Nn + q0;

    const char* kbase = (const char*)(kin + (size_t)b * Nn * Dd);
    const char* vbase = (const char*)(vt + (size_t)b * Dd * Nn);
    const char* qbase = (const char*)(qg + ((size_t)b * Nn + q0) * Dd);

    auto STAGE = [&](int buf, int t) {
      char* dst = KVb + buf * 65536;
      const int k0 = kst + t * 64;
#pragma unroll
      for (int i = 0; i < 4; ++i) {
        int p = i * 8192 + tid * 16;
        int row = p >> 9;
        int sl = ((p & 511) >> 4) ^ (row & 31);
        gl_lds16(kbase + (size_t)(k0 + row) * 512 + (sl << 4), dst + p);
      }
#pragma unroll
      for (int i = 0; i < 4; ++i) {
        int p = i * 8192 + tid * 16;
        int r = p >> 9;
        int sl = ((p & 511) >> 4) ^ (r & 31);
        int cl = sl << 4;
        int d = r * 4 + (cl >> 7);
        int kbyte = cl & 127;
        gl_lds16(vbase + (size_t)d * (Nn * 2) + (size_t)k0 * 2 + kbyte, dst + 32768 + p);
      }
    };

    STAGE(0, 0);
#pragma unroll
    for (int i = 0; i < 8; ++i) {
      int p = i * 8192 + tid * 16;
      int row = p >> 9;
      int sl = ((p & 511) >> 4) ^ (row & 31);
      gl_lds16(qbase + (size_t)row * 512 + (sl << 4), KVb + 65536 + p);
    }
    asm volatile("s_waitcnt vmcnt(0)" ::: "memory");
    asm volatile("s_barrier" ::: "memory");

    half8 qreg[16];
    {
      const int row = wq * 32 + l31;
#pragma unroll
      for (int kt = 0; kt < 16; ++kt) {
        int byte = row * 512 + (((kt * 2 + h) ^ (row & 31)) << 4);
        qreg[kt] = *(const half8*)(KVb + 65536 + byte);
      }
    }
    asm volatile("s_waitcnt lgkmcnt(0)" ::: "memory");
    asm volatile("s_barrier" ::: "memory");

    f32x16 acc[4];
#pragma unroll
    for (int dg = 0; dg < 4; ++dg)
#pragma unroll
      for (int r = 0; r < 16; ++r) acc[dg][r] = 0.f;
    float m = -__builtin_inff();
    float lsum = 0.f;

    for (int t = 0; t < nt; ++t) {
      const int cur = t & 1;
      if (t + 1 < nt) {
        STAGE(cur ^ 1, t + 1);
        asm volatile("s_waitcnt vmcnt(8)" ::: "memory");
      } else {
        asm volatile("s_waitcnt vmcnt(0)" ::: "memory");
      }
      asm volatile("s_barrier" ::: "memory");  // A: tile t ready

      const char* Ks = KVb + cur * 65536;
      const char* Vs = Ks + 32768;
      const int k0 = kst + t * 64;

      f32x16 st;
#pragma unroll
      for (int r = 0; r < 16; ++r) st[r] = 0.f;
      if (!uni) {
        const int key = wk * 32 + l31;
        __builtin_amdgcn_s_setprio(1);
#pragma unroll
        for (int kt = 0; kt < 16; ++kt) {
          int byte = key * 512 + (((kt * 2 + h) ^ l31) << 4);
          half8 kf = *(const half8*)(Ks + byte);
          st = mfma32h(kf, qreg[kt], st);
        }
        __builtin_amdgcn_s_setprio(0);
        if (k0 + 64 > L) {
#pragma unroll
          for (int r = 0; r < 16; ++r) {
            int keyg = k0 + wk * 32 + (r & 3) + 8 * (r >> 2) + 4 * h;
            if (keyg >= L) st[r] = -1e6f;
          }
        }
      }

      // local softmax over own 32-key half (pair-combined); pm-normalized P
      float pm = st[0];
#pragma unroll
      for (int r = 1; r < 16; ++r) pm = fmaxf(pm, st[r]);
      pm = fmaxf(pm, __shfl_xor(pm, 32));
      float psum = 0.f;
#pragma unroll
      for (int r = 0; r < 16; ++r) {
        float p_ = __expf(st[r] - pm);
        st[r] = p_;
        psum += p_;
      }
      psum += __shfl_xor(psum, 32);

      // single exchange: P (local-max normalized) + (pm, psum)
#pragma unroll
      for (int i = 0; i < 8; ++i) {
        unsigned int pk = pkrtz(st[2 * i], st[2 * i + 1]);
        int kp = wk * 16 + 4 * (i >> 1) + (i & 1) + 2 * h;
        PL[wq * 1024 + kp * 32 + l31] = pk;
      }
      if (h == 0) {
        MLX[(wq * 2 + wk) * 64 + l31] = pm;
        MLX[(wq * 2 + wk) * 64 + 32 + l31] = psum;
      }
      asm volatile("s_waitcnt lgkmcnt(0)\ns_barrier" ::: "memory");  // C

      // fold both halves: m/l update (lane-local l)
      float pm0 = MLX[(wq * 2 + 0) * 64 + l31];
      float ps0 = MLX[(wq * 2 + 0) * 64 + 32 + l31];
      float pm1 = MLX[(wq * 2 + 1) * 64 + l31];
      float ps1 = MLX[(wq * 2 + 1) * 64 + 32 + l31];
      float mnew = fmaxf(m, fmaxf(pm0, pm1));
      float scale = __expf(m - mnew);  // m=-inf -> 0
      m = mnew;
      float s0 = __expf(pm0 - mnew), s1 = __expf(pm1 - mnew);
      lsum = lsum * scale + s0 * ps0 + s1 * ps1;

      // read P frags; rescale halves by s0/s1 (packed fp16 muls)
      union { unsigned int u[4]; half8 v; } pf0, pf1, pf2, pf3;
#pragma unroll
      for (int w = 0; w < 4; ++w) {
        pf0.u[w] = PL[wq * 1024 + (0 * 8 + h * 4 + w) * 32 + l31];
        pf1.u[w] = PL[wq * 1024 + (1 * 8 + h * 4 + w) * 32 + l31];
        pf2.u[w] = PL[wq * 1024 + (2 * 8 + h * 4 + w) * 32 + l31];
        pf3.u[w] = PL[wq * 1024 + (3 * 8 + h * 4 + w) * 32 + l31];
      }
      {
        _Float16 s0h = (_Float16)s0, s1h = (_Float16)s1;
        half8 sc0 = {s0h, s0h, s0h, s0h, s0h, s0h, s0h, s0h};
        half8 sc1 = {s1h, s1h, s1h, s1h, s1h, s1h, s1h, s1h};
        pf0.v *= sc0;
        pf1.v *= sc0;
        pf2.v *= sc1;
        pf3.v *= sc1;
      }

#pragma unroll
      for (int dg = 0; dg < 4; ++dg)
#pragma unroll
        for (int r = 0; r < 16; ++r) acc[dg][r] *= scale;

      __builtin_amdgcn_s_setprio(1);
#pragma unroll
      for (int dg = 0; dg < 4; ++dg) {
        int r = wk * 32 + dg * 8 + (l31 >> 2);
#pragma unroll
        for (int ks = 0; ks < 4; ++ks) {
          int slotv = (l31 & 3) * 8 + ks * 2 + h;
          half8 vf = *(const half8*)(Vs + r * 512 + ((slotv ^ (r & 31)) << 4));
          acc[dg] = mfma32h(vf, ks == 0 ? pf0.v : (ks == 1 ? pf1.v : (ks == 2 ? pf2.v : pf3.v)),
                            acc[dg]);
        }
      }
      __builtin_amdgcn_s_setprio(0);

      asm volatile("s_barrier" ::: "memory");  // D: protect KV[cur] + PL/MLX
    }

    // ---- epilogue (l is lane-local) ----
    float linv = 1.f / lsum;
    if (whole) {
      // marker for k_comb early-exit on this (b, q) range
      if (h == 0 && wk == 0) {
        size_t qq = (size_t)(b * 2) * Nn + q0 + wq * 32 + l31;
        ml[qq * 2 + 0] = 1e30f;
      }
      float* T = (float*)SMEM;  // [128 q][260 f32]
      {
        const int ql = wq * 32 + l31;
#pragma unroll
        for (int dg = 0; dg < 4; ++dg)
#pragma unroll
          for (int r = 0; r < 16; ++r) {
            int d = wk * 128 + dg * 32 + (r & 3) + 8 * (r >> 2) + 4 * h;
            T[ql * 260 + d] = acc[dg][r] * linv;
          }
      }
      asm volatile("s_waitcnt lgkmcnt(0)\ns_barrier" ::: "memory");
      {
        const int rb = tid >> 6;
        const int c4 = (tid & 63) * 4;
#pragma unroll
        for (int i = 0; i < 16; ++i) {
          int row = rb + i * 8;
          float4v v = *(const float4v*)(T + row * 260 + c4);
          *(float4v*)(out + ((size_t)b * Nn + q0 + row) * Dd + c4) = v;
        }
      }
    } else {
      if (h == 0 && wk == 0) {
        size_t qq = prow + wq * 32 + l31;
        ml[qq * 2 + 0] = m;
        ml[qq * 2 + 1] = lsum;
      }
      _Float16* T = (_Float16*)SMEM;  // [128 q][264 fp16]
      {
        const int ql = wq * 32 + l31;
#pragma unroll
        for (int dg = 0; dg < 4; ++dg)
#pragma unroll
          for (int r = 0; r < 16; ++r) {
            int d = wk * 128 + dg * 32 + (r & 3) + 8 * (r >> 2) + 4 * h;
            T[ql * 264 + d] = (_Float16)(acc[dg][r] * linv);
          }
      }
      asm volatile("s_waitcnt lgkmcnt(0)\ns_barrier" ::: "memory");
      {
        const int rb = tid >> 6;
        const int c4 = (tid & 63) * 4;
#pragma unroll
        for (int i = 0; i < 16; ++i) {
          int row = rb + i * 8;
          half4 v = *(const half4*)(T + row * 264 + c4);
          *(half4*)(Op + (prow + row) * Dd + c4) = v;
        }
      }
    }
    asm volatile("s_waitcnt lgkmcnt(0)\ns_barrier" ::: "memory");  // before next item
  }
}

// ---------- kernel 2b: combine split-batch partials (marker -> exit) ----------
__global__ __launch_bounds__(256) void k_comb(const _Float16* __restrict__ Op,
                                              const float* __restrict__ ml,
                                              float* __restrict__ out) {
  int rid = blockIdx.x * 4 + (threadIdx.x >> 6);  // b*2048+q
  int lane = threadIdx.x & 63;
  int b = rid >> 11, q = rid & 2047;
  size_t i0 = (size_t)(b * 2 + 0) * Nn + q;
  float m0 = ml[i0 * 2];
  if (m0 >= 1e29f) return;  // whole item: k_attn_f already wrote out
  size_t i1 = (size_t)(b * 2 + 1) * Nn + q;
  float l0 = ml[i0 * 2 + 1];
  float m1 = ml[i1 * 2], l1 = ml[i1 * 2 + 1];
  float M = fmaxf(m0, m1);
  float c0 = (l0 > 0.f) ? __expf(m0 - M) * l0 : 0.f;
  float c1 = (l1 > 0.f) ? __expf(m1 - M) * l1 : 0.f;
  float inv = 1.f / (c0 + c1);
  c0 *= inv;
  c1 *= inv;
  float4v o = {0.f, 0.f, 0.f, 0.f};
  if (c0 > 0.f) {
    half4 o0 = *(const half4*)(Op + i0 * 256 + lane * 4);
#pragma unroll
    for (int j = 0; j < 4; ++j) o[j] = c0 * (float)o0[j];
  }
  if (c1 > 0.f) {
    half4 o1 = *(const half4*)(Op + i1 * 256 + lane * 4);
#pragma unroll
    for (int j = 0; j < 4; ++j) o[j] += c1 * (float)o1[j];
  }
  *(float4v*)(out + ((size_t)b * Nn + q) * 256 + lane * 4) = o;
}

// ---------- kernel 2 (fallback, ws too small): round-7-style fused ----------
__global__ __launch_bounds__(512, 2) void k_attn(
    const _Float16* __restrict__ qg, const _Float16* __restrict__ kin,
    const _Float16* __restrict__ vt, const int* __restrict__ vlen,
    float* __restrict__ out) {
  __shared__ __align__(16) char SMEM[149504];
  char* const KVb = SMEM;
  unsigned int* const PL = (unsigned int*)(SMEM + 131072);
  float* const mex = (float*)(SMEM + 147456);
  float* const lex = (float*)(SMEM + 148480);

  const int tid = threadIdx.x;
  const int wave = tid >> 6, lane = tid & 63;
  const int l31 = lane & 31, h = lane >> 5;
  const int wq = wave >> 1, wk = wave & 1;
  const int id = blockIdx.x;
  const int g = id & 7;
  const int j = id >> 3;
  const int b = g + 8 * (j >> 4);
  const int q0 = (j & 15) * 128;
  const int L = vlen[b];
  const bool uni = (L == 0);
  const int Lk = uni ? Nn : L;
  const int nt = (Lk + 63) >> 6;

  const char* kbase = (const char*)(kin + (size_t)b * Nn * Dd);
  const char* vbase = (const char*)(vt + (size_t)b * Dd * Nn);
  const char* qbase = (const char*)(qg + ((size_t)b * Nn + q0) * Dd);

  auto STAGE = [&](int buf, int t) {
    char* dst = KVb + buf * 65536;
    const int k0 = t * 64;
#pragma unroll
    for (int i = 0; i < 4; ++i) {
      int p = i * 8192 + tid * 16;
      int row = p >> 9;
      int sl = ((p & 511) >> 4) ^ (row & 31);
      gl_lds16(kbase + (size_t)(k0 + row) * 512 + (sl << 4), dst + p);
    }
#pragma unroll
    for (int i = 0; i < 4; ++i) {
      int p = i * 8192 + tid * 16;
      int r = p >> 9;
      int sl = ((p & 511) >> 4) ^ (r & 31);
      int cl = sl << 4;
      int d = r * 4 + (cl >> 7);
      int kbyte = cl & 127;
      gl_lds16(vbase + (size_t)d * (Nn * 2) + (size_t)k0 * 2 + kbyte, dst + 32768 + p);
    }
  };

  STAGE(0, 0);
#pragma unroll
  for (int i = 0; i < 8; ++i) {
    int p = i * 8192 + tid * 16;
    int row = p >> 9;
    int sl = ((p & 511) >> 4) ^ (row & 31);
    gl_lds16(qbase + (size_t)row * 512 + (sl << 4), KVb + 65536 + p);
  }
  asm volatile("s_waitcnt vmcnt(0)" ::: "memory");
  asm volatile("s_barrier" ::: "memory");

  half8 qreg[16];
  {
    const int row = wq * 32 + l31;
#pragma unroll
    for (int kt = 0; kt < 16; ++kt) {
      int byte = row * 512 + (((kt * 2 + h) ^ (row & 31)) << 4);
      qreg[kt] = *(const half8*)(KVb + 65536 + byte);
    }
  }
  asm volatile("s_waitcnt lgkmcnt(0)" ::: "memory");
  asm volatile("s_barrier" ::: "memory");

  f32x16 acc[4];
#pragma unroll
  for (int dg = 0; dg < 4; ++dg)
#pragma unroll
    for (int r = 0; r < 16; ++r) acc[dg][r] = 0.f;
  float m = -__builtin_inff();
  float lsum = 0.f;

  for (int t = 0; t < nt; ++t) {
    const int cur = t & 1;
    if (t + 1 < nt) {
      STAGE(cur ^ 1, t + 1);
      asm volatile("s_waitcnt vmcnt(8)" ::: "memory");
    } else {
      asm volatile("s_waitcnt vmcnt(0)" ::: "memory");
    }
    asm volatile("s_barrier" ::: "memory");

    const char* Ks = KVb + cur * 65536;
    const char* Vs = Ks + 32768;
    const int k0 = t * 64;

    f32x16 st;
#pragma unroll
    for (int r = 0; r < 16; ++r) st[r] = 0.f;
    if (!uni) {
      const int key = wk * 32 + l31;
      __builtin_amdgcn_s_setprio(1);
#pragma unroll
      for (int kt = 0; kt < 16; ++kt) {
        int byte = key * 512 + (((kt * 2 + h) ^ l31) << 4);
        half8 kf = *(const half8*)(Ks + byte);
        st = mfma32h(kf, qreg[kt], st);
      }
      __builtin_amdgcn_s_setprio(0);
      if (k0 + 64 > L) {
#pragma unroll
        for (int r = 0; r < 16; ++r) {
          int keyg = k0 + wk * 32 + (r & 3) + 8 * (r >> 2) + 4 * h;
          if (keyg >= L) st[r] = -1e6f;
        }
      }
    }

    float pm = st[0];
#pragma unroll
    for (int r = 1; r < 16; ++r) pm = fmaxf(pm, st[r]);
    pm = fmaxf(pm, __shfl_xor(pm, 32));
    if (lane < 32) mex[wave * 32 + lane] = pm;
    asm volatile("s_waitcnt lgkmcnt(0)\ns_barrier" ::: "memory");
    float pmo = mex[(wave ^ 1) * 32 + l31];
    float mnew = fmaxf(m, fmaxf(pm, pmo));
    float scale = __expf(m - mnew);
    m = mnew;
    float psum = 0.f;
#pragma unroll
    for (int r = 0; r < 16; ++r) {
      float p_ = __expf(st[r] - mnew);
      st[r] = p_;
      psum += p_;
    }
    lsum = lsum * scale + psum;

#pragma unroll
    for (int i = 0; i < 8; ++i) {
      unsigned int pk = pkrtz(st[2 * i], st[2 * i + 1]);
      int kp = wk * 16 + 4 * (i >> 1) + (i & 1) + 2 * h;
      PL[wq * 1024 + kp * 32 + l31] = pk;
    }
    asm volatile("s_waitcnt lgkmcnt(0)\ns_barrier" ::: "memory");

    union { unsigned int u[4]; half8 v; } pf0, pf1, pf2, pf3;
#pragma unroll
    for (int w = 0; w < 4; ++w) {
      pf0.u[w] = PL[wq * 1024 + (0 * 8 + h * 4 + w) * 32 + l31];
      pf1.u[w] = PL[wq * 1024 + (1 * 8 + h * 4 + w) * 32 + l31];
      pf2.u[w] = PL[wq * 1024 + (2 * 8 + h * 4 + w) * 32 + l31];
      pf3.u[w] = PL[wq * 1024 + (3 * 8 + h * 4 + w) * 32 + l31];
    }

#pragma unroll
    for (int dg = 0; dg < 4; ++dg)
#pragma unroll
      for (int r = 0; r < 16; ++r) acc[dg][r] *= scale;

    __builtin_amdgcn_s_setprio(1);
#pragma unroll
    for (int dg = 0; dg < 4; ++dg) {
      int r = wk * 32 + dg * 8 + (l31 >> 2);
#pragma unroll
      for (int ks = 0; ks < 4; ++ks) {
        int slotv = (l31 & 3) * 8 + ks * 2 + h;
        half8 vf = *(const half8*)(Vs + r * 512 + ((slotv ^ (r & 31)) << 4));
        acc[dg] = mfma32h(vf, ks == 0 ? pf0.v : (ks == 1 ? pf1.v : (ks == 2 ? pf2.v : pf3.v)),
                          acc[dg]);
      }
    }
    __builtin_amdgcn_s_setprio(0);

    asm volatile("s_barrier" ::: "memory");
  }

  lsum += __shfl_xor(lsum, 32);
  if (lane < 32) lex[wave * 32 + lane] = lsum;
  asm volatile("s_waitcnt lgkmcnt(0)\ns_barrier" ::: "memory");
  float linv = 1.f / (lsum + lex[(wave ^ 1) * 32 + l31]);

  float* T = (float*)SMEM;
  {
    const int ql = wq * 32 + l31;
#pragma unroll
    for (int dg = 0; dg < 4; ++dg)
#pragma unroll
      for (int r = 0; r < 16; ++r) {
        int d = wk * 128 + dg * 32 + (r & 3) + 8 * (r >> 2) + 4 * h;
        T[ql * 260 + d] = acc[dg][r] * linv;
      }
  }
  asm volatile("s_waitcnt lgkmcnt(0)\ns_barrier" ::: "memory");

  {
    const int rb = tid >> 6;
    const int c4 = (tid & 63) * 4;
#pragma unroll
    for (int i = 0; i < 16; ++i) {
      int row = rb + i * 8;
      float4v v = *(const float4v*)(T + row * 260 + c4);
      *(float4v*)(out + ((size_t)b * Nn + q0 + row) * Dd + c4) = v;
    }
  }
}

// ---------- launch ----------
extern "C" void kernel_launch(void* const* d_in, const int* in_sizes, int n_in,
                              void* d_out, int out_size, void* d_ws, size_t ws_size,
                              hipStream_t stream) {
  const float* x = (const float*)d_in[0];
  const int* vlen = (const int*)d_in[1];
  const float* Wq = (const float*)d_in[2];
  const float* bq = (const float*)d_in[3];
  const float* Wk = (const float*)d_in[4];
  const float* bk = (const float*)d_in[5];
  const float* Wv = (const float*)d_in[6];
  const float* bv = (const float*)d_in[7];
  float* out = (float*)d_out;
  char* ws = (char*)d_ws;

  _Float16* qh = (_Float16*)(ws);
  _Float16* kk = (_Float16*)(ws + 16777216);
  _Float16* vt = (_Float16*)(ws + 33554432);
  _Float16* wh = (_Float16*)(ws + 50331648);
  _Float16* Op = (_Float16*)(ws + 51380224);  // 32 MB
  float* ml = (float*)(ws + 84934656);        // 512 KB
  int* sched = (int*)(ws + 85458944);         // 2 KB
  _Float16* xh = (_Float16*)d_out;            // scratch; overwritten at the end

  k_split<<<8961, 256, 0, stream>>>(x, Wq, Wk, Wv, vlen, xh, wh, sched);
  k_qkv<<<dim3(256, 2, 3), 256, 0, stream>>>(xh, wh, bq, bk, bv, qh, kk, vt);
  if (ws_size >= 85460992ull) {
    k_attn_f<<<256, 512, 0, stream>>>(qh, kk, vt, vlen, sched, Op, ml, out);
    k_comb<<<8192, 256, 0, stream>>>(Op, ml, out);
  } else {
    k_attn<<<256, 512, 0, stream>>>(qh, kk, vt, vlen, out);
  }
}